// Round 16
// baseline (243.643 us; speedup 1.0000x reference)
//
#include <hip/hip_runtime.h>
#include <cstdint>

// Problem constants: B=4, S=1024, D=768, H=12, dh=64
#define BB 4
#define SS 1024
#define DD 768
#define HH 12
#define DH 64

typedef unsigned short u16;
typedef unsigned int   u32;
typedef __attribute__((ext_vector_type(8))) short bf16x8;
typedef __attribute__((ext_vector_type(4))) float f32x4;

// fp32 -> bf16 RNE (finite values)
__device__ __forceinline__ u16 f2bf(float f) {
    u32 u = __float_as_uint(f);
    u += 0x7fffu + ((u >> 16) & 1u);
    return (u16)(u >> 16);
}
__device__ __forceinline__ float b2f(u32 lo16) {
    return __uint_as_float(lo16 << 16);
}
__device__ __forceinline__ u32 pack2(float a, float b) {
    return (u32)f2bf(a) | ((u32)f2bf(b) << 16);
}

// async global->LDS, 16 B per lane. GLOBAL pointer is PER-LANE; LDS dest is
// wave-uniform base, HW adds lane*16 (m104/m108).
#define ASYNC16(gp, lp) __builtin_amdgcn_global_load_lds( \
    (const __attribute__((address_space(1))) void*)(gp),  \
    (__attribute__((address_space(3))) void*)(lp), 16, 0, 0)

// ---------------- MFMA GEMM body (NT: A[M,K], B[N,K], both K-contiguous bf16) ----
// BK=32. Tile BM_ x BN_, 256 threads = 4 waves in 2x2.
// mfma_f32_16x16x32_bf16; frag layouts per learn_hip m89/m91:
//   A: lane holds A[m=lane&15][k=(lane>>4)*8 + j]
//   B: lane holds Bt[n=lane&15][k=(lane>>4)*8 + j]  (NT rows)
//   C/D: col = lane&15, row = (lane>>4)*4 + reg
template<int BM_, int BN_, class Epi>
__device__ __forceinline__ void mfma_gemm(
    const u16* __restrict__ A, const u16* __restrict__ B,
    int K, int lda, int ldb, int m0, int n0, const Epi& epi)
{
    constexpr int MI = BM_ / 32;
    constexpr int NJ = BN_ / 32;
    __shared__ u16 Alds[BM_ * 32];
    __shared__ u16 Blds[BN_ * 32];

    const int tid  = threadIdx.x;
    const int wave = tid >> 6;
    const int lane = tid & 63;
    const int wr = wave >> 1, wc = wave & 1;

    const int ar = lane >> 2;
    const int ac = (lane & 3) * 8;

    f32x4 acc[MI][NJ] = {};

    for (int k0 = 0; k0 < K; k0 += 32) {
        __syncthreads();
#pragma unroll
        for (int j = 0; j < BM_ / 64; ++j) {
            const int rb = wave * (BM_ / 4) + j * 16;
            ASYNC16(A + (size_t)(m0 + rb + ar) * lda + k0 + ac, &Alds[rb * 32]);
        }
#pragma unroll
        for (int j = 0; j < BN_ / 64; ++j) {
            const int rb = wave * (BN_ / 4) + j * 16;
            ASYNC16(B + (size_t)(n0 + rb + ar) * ldb + k0 + ac, &Blds[rb * 32]);
        }
        __syncthreads();

        bf16x8 af[MI], bfr[NJ];
#pragma unroll
        for (int mi = 0; mi < MI; ++mi)
            af[mi] = *(const bf16x8*)&Alds[(wr * (BM_ / 2) + mi * 16 + (lane & 15)) * 32 + (lane >> 4) * 8];
#pragma unroll
        for (int nj = 0; nj < NJ; ++nj)
            bfr[nj] = *(const bf16x8*)&Blds[(wc * (BN_ / 2) + nj * 16 + (lane & 15)) * 32 + (lane >> 4) * 8];
#pragma unroll
        for (int mi = 0; mi < MI; ++mi)
#pragma unroll
            for (int nj = 0; nj < NJ; ++nj)
                acc[mi][nj] = __builtin_amdgcn_mfma_f32_16x16x32_bf16(
                    af[mi], bfr[nj], acc[mi][nj], 0, 0, 0);
    }

#pragma unroll
    for (int mi = 0; mi < MI; ++mi)
#pragma unroll
        for (int nj = 0; nj < NJ; ++nj)
#pragma unroll
            for (int r = 0; r < 4; ++r)
                epi(m0 + wr * (BM_ / 2) + mi * 16 + (lane >> 4) * 4 + r,
                    n0 + wc * (BN_ / 2) + nj * 16 + (lane & 15),
                    acc[mi][nj][r]);
}

// padded Clds row length (u16)
#define CPAD 136

// ---------------- qkv GEMM (custom, LDS-coalesced epilogue) ----------------
__global__ __launch_bounds__(256) void qkv_gemm_kernel(
    const u16* __restrict__ xb, const u16* __restrict__ Wt,
    const float* __restrict__ bias,
    u16* __restrict__ qb, u16* __restrict__ kb, u16* __restrict__ vb)
{
    __shared__ u16 Alds[128 * 32];
    __shared__ u16 Blds[128 * 32];
    __shared__ u16 Clds[128 * CPAD];

    const int tid  = threadIdx.x;
    const int wave = tid >> 6;
    const int lane = tid & 63;
    const int wr = wave >> 1, wc = wave & 1;
    const int ar = lane >> 2;
    const int ac = (lane & 3) * 8;
    const int m0 = blockIdx.y * 128, n0 = blockIdx.x * 128;

    f32x4 acc[4][4] = {};

    for (int k0 = 0; k0 < DD; k0 += 32) {
        __syncthreads();
#pragma unroll
        for (int j = 0; j < 2; ++j) {
            const int rb = wave * 32 + j * 16;
            ASYNC16(xb + (size_t)(m0 + rb + ar) * DD + k0 + ac, &Alds[rb * 32]);
            ASYNC16(Wt + (size_t)(n0 + rb + ar) * DD + k0 + ac, &Blds[rb * 32]);
        }
        __syncthreads();

        bf16x8 af[4], bfr[4];
#pragma unroll
        for (int mi = 0; mi < 4; ++mi)
            af[mi] = *(const bf16x8*)&Alds[(wr * 64 + mi * 16 + (lane & 15)) * 32 + (lane >> 4) * 8];
#pragma unroll
        for (int nj = 0; nj < 4; ++nj)
            bfr[nj] = *(const bf16x8*)&Blds[(wc * 64 + nj * 16 + (lane & 15)) * 32 + (lane >> 4) * 8];
#pragma unroll
        for (int mi = 0; mi < 4; ++mi)
#pragma unroll
            for (int nj = 0; nj < 4; ++nj)
                acc[mi][nj] = __builtin_amdgcn_mfma_f32_16x16x32_bf16(
                    af[mi], bfr[nj], acc[mi][nj], 0, 0, 0);
    }

    const int c  = n0 / DD;
    const int w0 = n0 - c * DD;
    const int hA = w0 >> 6;
    const float qs = (c == 0) ? 0.125f : 1.0f;
#pragma unroll
    for (int mi = 0; mi < 4; ++mi)
#pragma unroll
        for (int nj = 0; nj < 4; ++nj)
#pragma unroll
            for (int r = 0; r < 4; ++r) {
                const int row = wr * 64 + mi * 16 + (lane >> 4) * 4 + r;
                const int col = wc * 64 + nj * 16 + (lane & 15);
                Clds[row * CPAD + col] = f2bf((acc[mi][nj][r] + bias[n0 + col]) * qs);
            }
    __syncthreads();

    u16* const dst = (c == 0) ? qb : (c == 1) ? kb : vb;
    const int b = m0 >> 10;
#pragma unroll
    for (int j = 0; j < 8; ++j) {
        const int idx = j * 256 + tid;
        const int row = idx >> 4, u4 = idx & 15;
        const int half = u4 >> 3, d8 = u4 & 7;
        const int h = hA + half;
        const int s = (m0 + row) & 1023;
        const uint4 v = *(const uint4*)&Clds[row * CPAD + half * 64 + d8 * 8];
        *(uint4*)&dst[(((size_t)(b * HH + h) << 10) + s) * DH + d8 * 8] = v;
    }
}

// ---------------- vb -> vt transpose (per bh: 1024x64 -> 64x1024) ----------
__global__ __launch_bounds__(256) void vtrans_kernel(
    const u16* __restrict__ vb, u16* __restrict__ vt)
{
    __shared__ u16 t[64 * 72];
    const int tid = threadIdx.x;
    const int bh = blockIdx.y;
    const int s0 = blockIdx.x * 64;
    const u16* src = vb + ((size_t)bh << 16) + (size_t)s0 * DH;

#pragma unroll
    for (int j = 0; j < 2; ++j) {
        const int idx = j * 256 + tid;
        const int row = idx >> 3, u4 = idx & 7;
        *(uint4*)&t[row * 72 + u4 * 8] = *(const uint4*)&src[row * DH + u4 * 8];
    }
    __syncthreads();

#pragma unroll
    for (int j = 0; j < 2; ++j) {
        const int idx = j * 256 + tid;
        const int d = idx >> 3, u4 = idx & 7;
        u16 tmp[8];
#pragma unroll
        for (int i = 0; i < 8; ++i) tmp[i] = t[(u4 * 8 + i) * 72 + d];
        *(uint4*)&vt[((size_t)bh * DH + d) * SS + s0 + u4 * 8] = *(const uint4*)tmp;
    }
}

// ---------------- qk GEMM (custom, LDS-coalesced epilogue) -----------------
__global__ __launch_bounds__(256) void qk_gemm_kernel(
    const u16* __restrict__ qb, const u16* __restrict__ kb,
    u16* __restrict__ attn, int bh0)
{
    __shared__ u16 Alds[128 * 32];
    __shared__ u16 Blds[128 * 32];
    __shared__ u16 Clds[128 * CPAD];

    const int tid  = threadIdx.x;
    const int wave = tid >> 6;
    const int lane = tid & 63;
    const int wr = wave >> 1, wc = wave & 1;
    const int ar = lane >> 2;
    const int ac = (lane & 3) * 8;
    const int m0 = blockIdx.y * 128, n0 = blockIdx.x * 128;

    const int bhL = blockIdx.z;
    const u16* A = qb + (size_t)(bh0 + bhL) * SS * DH;
    const u16* B = kb + (size_t)(bh0 + bhL) * SS * DH;
    u16* C = attn + (size_t)bhL * SS * SS;

    f32x4 acc[4][4] = {};

#pragma unroll
    for (int k0 = 0; k0 < DH; k0 += 32) {
        __syncthreads();
#pragma unroll
        for (int j = 0; j < 2; ++j) {
            const int rb = wave * 32 + j * 16;
            ASYNC16(A + (size_t)(m0 + rb + ar) * DH + k0 + ac, &Alds[rb * 32]);
            ASYNC16(B + (size_t)(n0 + rb + ar) * DH + k0 + ac, &Blds[rb * 32]);
        }
        __syncthreads();

        bf16x8 af[4], bfr[4];
#pragma unroll
        for (int mi = 0; mi < 4; ++mi)
            af[mi] = *(const bf16x8*)&Alds[(wr * 64 + mi * 16 + (lane & 15)) * 32 + (lane >> 4) * 8];
#pragma unroll
        for (int nj = 0; nj < 4; ++nj)
            bfr[nj] = *(const bf16x8*)&Blds[(wc * 64 + nj * 16 + (lane & 15)) * 32 + (lane >> 4) * 8];
#pragma unroll
        for (int mi = 0; mi < 4; ++mi)
#pragma unroll
            for (int nj = 0; nj < 4; ++nj)
                acc[mi][nj] = __builtin_amdgcn_mfma_f32_16x16x32_bf16(
                    af[mi], bfr[nj], acc[mi][nj], 0, 0, 0);
    }

#pragma unroll
    for (int mi = 0; mi < 4; ++mi)
#pragma unroll
        for (int nj = 0; nj < 4; ++nj)
#pragma unroll
            for (int r = 0; r < 4; ++r) {
                const int row = wr * 64 + mi * 16 + (lane >> 4) * 4 + r;
                const int col = wc * 64 + nj * 16 + (lane & 15);
                Clds[row * CPAD + col] = f2bf(acc[mi][nj][r]);
            }
    __syncthreads();

#pragma unroll
    for (int j = 0; j < 8; ++j) {
        const int idx = j * 256 + tid;
        const int row = idx >> 4, u4 = idx & 15;
        *(uint4*)&C[(size_t)(m0 + row) * SS + n0 + u4 * 8] =
            *(const uint4*)&Clds[row * CPAD + u4 * 8];
    }
}

// ---------------- pv (64x64 tile) ------------------------------------------
__global__ __launch_bounds__(256) void pv_gemm_kernel(
    const u16* __restrict__ attn2, const u16* __restrict__ vt,
    u16* __restrict__ ctx, int bh0)
{
    const int bhL = blockIdx.z;
    const int bh = bh0 + bhL;
    const int b = bh / HH, h = bh % HH;
    const u16* A = attn2 + (size_t)bhL * SS * SS;
    const u16* B = vt + (size_t)bh * DH * SS;
    u16* C = ctx + (size_t)b * SS * DD + h * DH;
    struct Epi {
        u16* C;
        __device__ void operator()(int m, int n, float v) const {
            C[(size_t)m * DD + n] = f2bf(v);
        }
    } epi{C};
    mfma_gemm<64, 64>(A, B, SS, SS, SS, blockIdx.y * 64, 0, epi);
}

// ---------------- proj (template) ------------------------------------------
__global__ __launch_bounds__(256) void proj_gemm_kernel(
    const u16* __restrict__ ctx, const u16* __restrict__ Wt,
    const float* __restrict__ bias, float* __restrict__ out)
{
    struct Epi {
        float* out; const float* bias;
        __device__ void operator()(int m, int n, float v) const {
            out[(size_t)m * DD + n] = v + bias[n];
        }
    } epi{out, bias};
    mfma_gemm<128, 64>(ctx, Wt, DD, DD, DD, blockIdx.y * 128, blockIdx.x * 64, epi);
}

// ---------------- mix + softmax — MFMA version (R15 + padding fix) ---------
// R15 NaN root cause: zero-padded-A only masks padded B columns if they are
// FINITE (0 x NaN/Inf = NaN, and MFMA honors IEEE). St cols 12..23 and the +8
// tail were uninitialized LDS -> NaN poisoning. Fix: zero them at stage-in.
__global__ __launch_bounds__(256) void mix_softmax_kernel(
    const u16* __restrict__ attn, u16* __restrict__ attn2,
    const float* __restrict__ Wl, const float* __restrict__ bl,
    const float* __restrict__ Ww, const float* __restrict__ bw)
{
    __shared__ __attribute__((aligned(16))) u16 St[1024 * 24 + 8];
    __shared__ __attribute__((aligned(16))) u16 WlT[16 * 32];
    __shared__ __attribute__((aligned(16))) u16 WwT[16 * 32];
    __shared__ float blS[16], bwS[16];
    __shared__ float redS[4][16];

    const int tid  = threadIdx.x;
    const int wave = tid >> 6;
    const int lane = tid & 63;
    const int p    = lane >> 4;          // quarter-wave
    const int bL = blockIdx.x >> 10;
    const int qi = blockIdx.x & (SS - 1);
    const size_t gbase = ((size_t)bL * HH * SS + qi) * SS + tid * 4;

    // weights: WlT[g][h] = Wl[h][g], zero-padded to [16][32]
    for (int e = tid; e < 512; e += 256) {
        const int g = e >> 5, h = e & 31;
        WlT[e] = (g < HH && h < HH) ? f2bf(Wl[h * HH + g]) : (u16)0;
    }
    if (tid < 16) {
        blS[tid] = (tid < HH) ? bl[tid] : 0.f;
        bwS[tid] = (tid < HH) ? bw[tid] : 0.f;
    }

    // stage-in transposed: St[k][h] = attn[h][qi][k], k = tid*4..+3.
    // Zero pad cols 12..23 of each owned row (MFMA B reads them; must be
    // finite for the zero-A masking) + the 16 B tail.
    {
        const int k0 = tid * 4;
#pragma unroll
        for (int i = 0; i < 4; ++i) {
            *(uint2*)&St[(k0 + i) * 24 + 12] = make_uint2(0u, 0u);
            *(uint4*)&St[(k0 + i) * 24 + 16] = make_uint4(0u, 0u, 0u, 0u);
        }
        if (tid == 0)
            *(uint4*)&St[1024 * 24] = make_uint4(0u, 0u, 0u, 0u);
#pragma unroll
        for (int h = 0; h < HH; ++h) {
            const uint2 u = *(const uint2*)&attn[gbase + (size_t)h * SS * SS];
            St[(k0 + 0) * 24 + h] = (u16)(u.x & 0xffff);
            St[(k0 + 1) * 24 + h] = (u16)(u.x >> 16);
            St[(k0 + 2) * 24 + h] = (u16)(u.y & 0xffff);
            St[(k0 + 3) * 24 + h] = (u16)(u.y >> 16);
        }
    }
    __syncthreads();

    // ---- mix1 + exp + partial rowsums (16 frags per wave, in place)
    const bf16x8 af1 = *(const bf16x8*)&WlT[(lane & 15) * 32 + p * 8];
    float blr[4];
#pragma unroll
    for (int r = 0; r < 4; ++r) blr[r] = blS[p * 4 + r];
    float psum[4] = {0.f, 0.f, 0.f, 0.f};
    const int kbase = wave * 256;
    const f32x4 zero = {};

#pragma unroll
    for (int f = 0; f < 16; ++f) {
        const int k = kbase + f * 16 + (lane & 15);
        const bf16x8 bfr = *(const bf16x8*)&St[k * 24 + p * 8];
        const f32x4 d = __builtin_amdgcn_mfma_f32_16x16x32_bf16(af1, bfr, zero, 0, 0, 0);
        const float e0 = __expf(d[0] + blr[0]), e1 = __expf(d[1] + blr[1]);
        const float e2 = __expf(d[2] + blr[2]), e3 = __expf(d[3] + blr[3]);
        psum[0] += e0; psum[1] += e1; psum[2] += e2; psum[3] += e3;
        uint2 pk;
        pk.x = pack2(e0, e1); pk.y = pack2(e2, e3);
        *(uint2*)&St[k * 24 + p * 4] = pk;     // e into cols g=p*4..+3
    }

    // rowsum butterfly over lane&15 (16 k-cols), then per-wave partials
#pragma unroll
    for (int r = 0; r < 4; ++r)
#pragma unroll
        for (int off = 1; off < 16; off <<= 1)
            psum[r] += __shfl_xor(psum[r], off);
    if ((lane & 15) == 0)
#pragma unroll
        for (int r = 0; r < 4; ++r) redS[wave][p * 4 + r] = psum[r];
    __syncthreads();

    // mix2 weights with folded normalization: WwT'[g][h] = Ww[h][g] / l[h]
    for (int e = tid; e < 512; e += 256) {
        const int g = e >> 5, h = e & 31;
        u16 v = 0;
        if (g < HH && h < HH) {
            const float l = (redS[0][h] + redS[1][h]) + (redS[2][h] + redS[3][h]);
            v = f2bf(Ww[h * HH + g] / l);
        }
        WwT[e] = v;
    }
    __syncthreads();

    // ---- mix2 (16 frags per wave, in place: cols p*8.. read, p*4.. written)
    const bf16x8 af2 = *(const bf16x8*)&WwT[(lane & 15) * 32 + p * 8];
    float bwr[4];
#pragma unroll
    for (int r = 0; r < 4; ++r) bwr[r] = bwS[p * 4 + r];

#pragma unroll
    for (int f = 0; f < 16; ++f) {
        const int k = kbase + f * 16 + (lane & 15);
        const bf16x8 bfr = *(const bf16x8*)&St[k * 24 + p * 8];
        const f32x4 d = __builtin_amdgcn_mfma_f32_16x16x32_bf16(af2, bfr, zero, 0, 0, 0);
        uint2 pk;
        pk.x = pack2(d[0] + bwr[0], d[1] + bwr[1]);
        pk.y = pack2(d[2] + bwr[2], d[3] + bwr[3]);
        *(uint2*)&St[k * 24 + p * 4] = pk;     // attn2 into cols g=p*4..+3
    }
    __syncthreads();

    // copy-out: St[k][g] -> attn2[g][qi][k] (coalesced uint2 per head)
    {
        const int k0 = tid * 4;
#pragma unroll
        for (int g = 0; g < HH; ++g) {
            uint2 o;
            o.x = (u32)St[(k0 + 0) * 24 + g] | ((u32)St[(k0 + 1) * 24 + g] << 16);
            o.y = (u32)St[(k0 + 2) * 24 + g] | ((u32)St[(k0 + 3) * 24 + g] << 16);
            *(uint2*)&attn2[gbase + (size_t)g * SS * SS] = o;
        }
    }
}

// ---------------- conversion kernels ----------------

__global__ __launch_bounds__(256) void cvt_bf16_kernel(
    const float* __restrict__ in, u16* __restrict__ out, int n8)
{
    const int i = blockIdx.x * 256 + threadIdx.x;
    if (i >= n8) return;
    const float4 a = ((const float4*)in)[i * 2];
    const float4 b = ((const float4*)in)[i * 2 + 1];
    uint4 p;
    p.x = pack2(a.x, a.y); p.y = pack2(a.z, a.w);
    p.z = pack2(b.x, b.y); p.w = pack2(b.z, b.w);
    ((uint4*)out)[i] = p;
}

__global__ __launch_bounds__(256) void cvt_transpose_kernel(
    const float* __restrict__ in, u16* __restrict__ out, int R, int C)
{
    __shared__ float t[32][33];
    const int c0 = blockIdx.x * 32, r0 = blockIdx.y * 32;
    const int tr = threadIdx.x >> 3;
    const int tc = (threadIdx.x & 7) * 4;
    const float4 v = *(const float4*)&in[(size_t)(r0 + tr) * C + c0 + tc];
    t[tc + 0][tr] = v.x; t[tc + 1][tr] = v.y;
    t[tc + 2][tr] = v.z; t[tc + 3][tr] = v.w;
    __syncthreads();
    uint2 p;
    p.x = pack2(t[tr][tc + 0], t[tr][tc + 1]);
    p.y = pack2(t[tr][tc + 2], t[tr][tc + 3]);
    *(uint2*)&out[(size_t)(c0 + tr) * R + r0 + tc] = p;
}

// ---------------- launch ----------------
extern "C" void kernel_launch(void* const* d_in, const int* in_sizes, int n_in,
                              void* d_out, int out_size, void* d_ws, size_t ws_size,
                              hipStream_t stream)
{
    const float* x     = (const float*)d_in[0];
    const float* Wqkv  = (const float*)d_in[1];
    const float* bqkv  = (const float*)d_in[2];
    const float* Wl    = (const float*)d_in[3];
    const float* bl    = (const float*)d_in[4];
    const float* Ww    = (const float*)d_in[5];
    const float* bw    = (const float*)d_in[6];
    const float* Wproj = (const float*)d_in[7];
    const float* bproj = (const float*)d_in[8];
    float* out = (float*)d_out;

    // workspace (bf16 elems)
    const size_t N_XB  = (size_t)BB * SS * DD;
    const size_t N_QB  = (size_t)BB * HH * SS * DH;
    const size_t N_WT  = (size_t)DD * 3 * DD;
    const size_t N_WP  = (size_t)DD * DD;
    const size_t N_AT1 = (size_t)HH * SS * SS;

    u16* xb  = (u16*)d_ws;
    u16* qb  = xb  + N_XB;
    u16* kb  = qb  + N_QB;
    u16* vb  = kb  + N_QB;
    u16* vt  = vb  + N_QB;
    u16* ctx = vt  + N_QB;
    u16* Wqkv_t = ctx + N_XB;
    u16* Wproj_t = Wqkv_t + N_WT;
    u16* attn = Wproj_t + N_WP;

    const size_t fixed_bytes = (size_t)(N_XB * 2 + N_QB * 4 + N_WT + N_WP) * 2;
    int b_per = BB;
    while (b_per > 1 &&
           fixed_bytes + (size_t)b_per * N_AT1 * 2 * 2 > ws_size)
        b_per >>= 1;
    const int n_iter = BB / b_per;
    u16* attn2 = attn + (size_t)b_per * N_AT1;

    const dim3 blk(256);

    // 0) conversions
    cvt_bf16_kernel<<<dim3((N_XB / 8 + 255) / 256), blk, 0, stream>>>(x, xb, (int)(N_XB / 8));
    cvt_transpose_kernel<<<dim3(3 * DD / 32, DD / 32), blk, 0, stream>>>(Wqkv, Wqkv_t, DD, 3 * DD);
    cvt_transpose_kernel<<<dim3(DD / 32, DD / 32), blk, 0, stream>>>(Wproj, Wproj_t, DD, DD);

    // 1) QKV projection (qb scaled, kb, vb) + v transpose
    qkv_gemm_kernel<<<dim3(3 * DD / 128, BB * SS / 128), blk, 0, stream>>>(
        xb, Wqkv_t, bqkv, qb, kb, vb);
    vtrans_kernel<<<dim3(SS / 64, BB * HH), blk, 0, stream>>>(vb, vt);

    for (int it = 0; it < n_iter; ++it) {
        const int bh0 = it * b_per * HH;
        // 2) logits
        qk_gemm_kernel<<<dim3(SS / 128, SS / 128, b_per * HH), blk, 0, stream>>>(
            qb, kb, attn, bh0);
        // 3) mix1 + softmax + mix2 (MFMA mixes)
        mix_softmax_kernel<<<dim3(b_per * SS), blk, 0, stream>>>(
            attn, attn2, Wl, bl, Ww, bw);
        // 4) PV (64x64 tiles)
        pv_gemm_kernel<<<dim3(1, SS / 64, b_per * HH), blk, 0, stream>>>(
            attn2, vt, ctx, bh0);
    }

    // 5) output projection
    proj_gemm_kernel<<<dim3(DD / 64, BB * SS / 128), blk, 0, stream>>>(
        ctx, Wproj_t, bproj, out);
}

// Round 17
// 233.538 us; speedup vs baseline: 1.0433x; 1.0433x over previous
//
#include <hip/hip_runtime.h>
#include <cstdint>

// Problem constants: B=4, S=1024, D=768, H=12, dh=64
#define BB 4
#define SS 1024
#define DD 768
#define HH 12
#define DH 64

typedef unsigned short u16;
typedef unsigned int   u32;
typedef __attribute__((ext_vector_type(8))) short bf16x8;
typedef __attribute__((ext_vector_type(4))) float f32x4;

// fp32 -> bf16 RNE (finite values)
__device__ __forceinline__ u16 f2bf(float f) {
    u32 u = __float_as_uint(f);
    u += 0x7fffu + ((u >> 16) & 1u);
    return (u16)(u >> 16);
}
__device__ __forceinline__ float b2f(u32 lo16) {
    return __uint_as_float(lo16 << 16);
}
__device__ __forceinline__ u32 pack2(float a, float b) {
    return (u32)f2bf(a) | ((u32)f2bf(b) << 16);
}

// async global->LDS, 16 B per lane. GLOBAL pointer is PER-LANE; LDS dest is
// wave-uniform base, HW adds lane*16 (m104/m108).
#define ASYNC16(gp, lp) __builtin_amdgcn_global_load_lds( \
    (const __attribute__((address_space(1))) void*)(gp),  \
    (__attribute__((address_space(3))) void*)(lp), 16, 0, 0)

// ---------------- MFMA GEMM body (NT: A[M,K], B[N,K], both K-contiguous bf16) ----
// BK=32. Tile BM_ x BN_, 256 threads = 4 waves in 2x2.
// mfma_f32_16x16x32_bf16; frag layouts per learn_hip m89/m91:
//   A: lane holds A[m=lane&15][k=(lane>>4)*8 + j]
//   B: lane holds Bt[n=lane&15][k=(lane>>4)*8 + j]  (NT rows)
//   C/D: col = lane&15, row = (lane>>4)*4 + reg
template<int BM_, int BN_, class Epi>
__device__ __forceinline__ void mfma_gemm(
    const u16* __restrict__ A, const u16* __restrict__ B,
    int K, int lda, int ldb, int m0, int n0, const Epi& epi)
{
    constexpr int MI = BM_ / 32;
    constexpr int NJ = BN_ / 32;
    __shared__ u16 Alds[BM_ * 32];
    __shared__ u16 Blds[BN_ * 32];

    const int tid  = threadIdx.x;
    const int wave = tid >> 6;
    const int lane = tid & 63;
    const int wr = wave >> 1, wc = wave & 1;

    const int ar = lane >> 2;
    const int ac = (lane & 3) * 8;

    f32x4 acc[MI][NJ] = {};

    for (int k0 = 0; k0 < K; k0 += 32) {
        __syncthreads();
#pragma unroll
        for (int j = 0; j < BM_ / 64; ++j) {
            const int rb = wave * (BM_ / 4) + j * 16;
            ASYNC16(A + (size_t)(m0 + rb + ar) * lda + k0 + ac, &Alds[rb * 32]);
        }
#pragma unroll
        for (int j = 0; j < BN_ / 64; ++j) {
            const int rb = wave * (BN_ / 4) + j * 16;
            ASYNC16(B + (size_t)(n0 + rb + ar) * ldb + k0 + ac, &Blds[rb * 32]);
        }
        __syncthreads();

        bf16x8 af[MI], bfr[NJ];
#pragma unroll
        for (int mi = 0; mi < MI; ++mi)
            af[mi] = *(const bf16x8*)&Alds[(wr * (BM_ / 2) + mi * 16 + (lane & 15)) * 32 + (lane >> 4) * 8];
#pragma unroll
        for (int nj = 0; nj < NJ; ++nj)
            bfr[nj] = *(const bf16x8*)&Blds[(wc * (BN_ / 2) + nj * 16 + (lane & 15)) * 32 + (lane >> 4) * 8];
#pragma unroll
        for (int mi = 0; mi < MI; ++mi)
#pragma unroll
            for (int nj = 0; nj < NJ; ++nj)
                acc[mi][nj] = __builtin_amdgcn_mfma_f32_16x16x32_bf16(
                    af[mi], bfr[nj], acc[mi][nj], 0, 0, 0);
    }

#pragma unroll
    for (int mi = 0; mi < MI; ++mi)
#pragma unroll
        for (int nj = 0; nj < NJ; ++nj)
#pragma unroll
            for (int r = 0; r < 4; ++r)
                epi(m0 + wr * (BM_ / 2) + mi * 16 + (lane >> 4) * 4 + r,
                    n0 + wc * (BN_ / 2) + nj * 16 + (lane & 15),
                    acc[mi][nj][r]);
}

// padded Clds row length (u16)
#define CPAD 136

// ---------------- qkv GEMM (custom, LDS-coalesced epilogue) ----------------
__global__ __launch_bounds__(256) void qkv_gemm_kernel(
    const u16* __restrict__ xb, const u16* __restrict__ Wt,
    const float* __restrict__ bias,
    u16* __restrict__ qb, u16* __restrict__ kb, u16* __restrict__ vb)
{
    __shared__ u16 Alds[128 * 32];
    __shared__ u16 Blds[128 * 32];
    __shared__ u16 Clds[128 * CPAD];

    const int tid  = threadIdx.x;
    const int wave = tid >> 6;
    const int lane = tid & 63;
    const int wr = wave >> 1, wc = wave & 1;
    const int ar = lane >> 2;
    const int ac = (lane & 3) * 8;
    const int m0 = blockIdx.y * 128, n0 = blockIdx.x * 128;

    f32x4 acc[4][4] = {};

    for (int k0 = 0; k0 < DD; k0 += 32) {
        __syncthreads();
#pragma unroll
        for (int j = 0; j < 2; ++j) {
            const int rb = wave * 32 + j * 16;
            ASYNC16(xb + (size_t)(m0 + rb + ar) * DD + k0 + ac, &Alds[rb * 32]);
            ASYNC16(Wt + (size_t)(n0 + rb + ar) * DD + k0 + ac, &Blds[rb * 32]);
        }
        __syncthreads();

        bf16x8 af[4], bfr[4];
#pragma unroll
        for (int mi = 0; mi < 4; ++mi)
            af[mi] = *(const bf16x8*)&Alds[(wr * 64 + mi * 16 + (lane & 15)) * 32 + (lane >> 4) * 8];
#pragma unroll
        for (int nj = 0; nj < 4; ++nj)
            bfr[nj] = *(const bf16x8*)&Blds[(wc * 64 + nj * 16 + (lane & 15)) * 32 + (lane >> 4) * 8];
#pragma unroll
        for (int mi = 0; mi < 4; ++mi)
#pragma unroll
            for (int nj = 0; nj < 4; ++nj)
                acc[mi][nj] = __builtin_amdgcn_mfma_f32_16x16x32_bf16(
                    af[mi], bfr[nj], acc[mi][nj], 0, 0, 0);
    }

    const int c  = n0 / DD;
    const int w0 = n0 - c * DD;
    const int hA = w0 >> 6;
    const float qs = (c == 0) ? 0.125f : 1.0f;
#pragma unroll
    for (int mi = 0; mi < 4; ++mi)
#pragma unroll
        for (int nj = 0; nj < 4; ++nj)
#pragma unroll
            for (int r = 0; r < 4; ++r) {
                const int row = wr * 64 + mi * 16 + (lane >> 4) * 4 + r;
                const int col = wc * 64 + nj * 16 + (lane & 15);
                Clds[row * CPAD + col] = f2bf((acc[mi][nj][r] + bias[n0 + col]) * qs);
            }
    __syncthreads();

    u16* const dst = (c == 0) ? qb : (c == 1) ? kb : vb;
    const int b = m0 >> 10;
#pragma unroll
    for (int j = 0; j < 8; ++j) {
        const int idx = j * 256 + tid;
        const int row = idx >> 4, u4 = idx & 15;
        const int half = u4 >> 3, d8 = u4 & 7;
        const int h = hA + half;
        const int s = (m0 + row) & 1023;
        const uint4 v = *(const uint4*)&Clds[row * CPAD + half * 64 + d8 * 8];
        *(uint4*)&dst[(((size_t)(b * HH + h) << 10) + s) * DH + d8 * 8] = v;
    }
}

// ---------------- vb -> vt transpose (per bh: 1024x64 -> 64x1024) ----------
__global__ __launch_bounds__(256) void vtrans_kernel(
    const u16* __restrict__ vb, u16* __restrict__ vt)
{
    __shared__ u16 t[64 * 72];
    const int tid = threadIdx.x;
    const int bh = blockIdx.y;
    const int s0 = blockIdx.x * 64;
    const u16* src = vb + ((size_t)bh << 16) + (size_t)s0 * DH;

#pragma unroll
    for (int j = 0; j < 2; ++j) {
        const int idx = j * 256 + tid;
        const int row = idx >> 3, u4 = idx & 7;
        *(uint4*)&t[row * 72 + u4 * 8] = *(const uint4*)&src[row * DH + u4 * 8];
    }
    __syncthreads();

#pragma unroll
    for (int j = 0; j < 2; ++j) {
        const int idx = j * 256 + tid;
        const int d = idx >> 3, u4 = idx & 7;
        u16 tmp[8];
#pragma unroll
        for (int i = 0; i < 8; ++i) tmp[i] = t[(u4 * 8 + i) * 72 + d];
        *(uint4*)&vt[((size_t)bh * DH + d) * SS + s0 + u4 * 8] = *(const uint4*)tmp;
    }
}

// ---------------- qk GEMM (custom, LDS-coalesced epilogue) -----------------
__global__ __launch_bounds__(256) void qk_gemm_kernel(
    const u16* __restrict__ qb, const u16* __restrict__ kb,
    u16* __restrict__ attn, int bh0)
{
    __shared__ u16 Alds[128 * 32];
    __shared__ u16 Blds[128 * 32];
    __shared__ u16 Clds[128 * CPAD];

    const int tid  = threadIdx.x;
    const int wave = tid >> 6;
    const int lane = tid & 63;
    const int wr = wave >> 1, wc = wave & 1;
    const int ar = lane >> 2;
    const int ac = (lane & 3) * 8;
    const int m0 = blockIdx.y * 128, n0 = blockIdx.x * 128;

    const int bhL = blockIdx.z;
    const u16* A = qb + (size_t)(bh0 + bhL) * SS * DH;
    const u16* B = kb + (size_t)(bh0 + bhL) * SS * DH;
    u16* C = attn + (size_t)bhL * SS * SS;

    f32x4 acc[4][4] = {};

#pragma unroll
    for (int k0 = 0; k0 < DH; k0 += 32) {
        __syncthreads();
#pragma unroll
        for (int j = 0; j < 2; ++j) {
            const int rb = wave * 32 + j * 16;
            ASYNC16(A + (size_t)(m0 + rb + ar) * DH + k0 + ac, &Alds[rb * 32]);
            ASYNC16(B + (size_t)(n0 + rb + ar) * DH + k0 + ac, &Blds[rb * 32]);
        }
        __syncthreads();

        bf16x8 af[4], bfr[4];
#pragma unroll
        for (int mi = 0; mi < 4; ++mi)
            af[mi] = *(const bf16x8*)&Alds[(wr * 64 + mi * 16 + (lane & 15)) * 32 + (lane >> 4) * 8];
#pragma unroll
        for (int nj = 0; nj < 4; ++nj)
            bfr[nj] = *(const bf16x8*)&Blds[(wc * 64 + nj * 16 + (lane & 15)) * 32 + (lane >> 4) * 8];
#pragma unroll
        for (int mi = 0; mi < 4; ++mi)
#pragma unroll
            for (int nj = 0; nj < 4; ++nj)
                acc[mi][nj] = __builtin_amdgcn_mfma_f32_16x16x32_bf16(
                    af[mi], bfr[nj], acc[mi][nj], 0, 0, 0);
    }

#pragma unroll
    for (int mi = 0; mi < 4; ++mi)
#pragma unroll
        for (int nj = 0; nj < 4; ++nj)
#pragma unroll
            for (int r = 0; r < 4; ++r) {
                const int row = wr * 64 + mi * 16 + (lane >> 4) * 4 + r;
                const int col = wc * 64 + nj * 16 + (lane & 15);
                Clds[row * CPAD + col] = f2bf(acc[mi][nj][r]);
            }
    __syncthreads();

#pragma unroll
    for (int j = 0; j < 8; ++j) {
        const int idx = j * 256 + tid;
        const int row = idx >> 4, u4 = idx & 15;
        *(uint4*)&C[(size_t)(m0 + row) * SS + n0 + u4 * 8] =
            *(const uint4*)&Clds[row * CPAD + u4 * 8];
    }
}

// ---------------- pv (64x64 tile) ------------------------------------------
__global__ __launch_bounds__(256) void pv_gemm_kernel(
    const u16* __restrict__ attn2, const u16* __restrict__ vt,
    u16* __restrict__ ctx, int bh0)
{
    const int bhL = blockIdx.z;
    const int bh = bh0 + bhL;
    const int b = bh / HH, h = bh % HH;
    const u16* A = attn2 + (size_t)bhL * SS * SS;
    const u16* B = vt + (size_t)bh * DH * SS;
    u16* C = ctx + (size_t)b * SS * DD + h * DH;
    struct Epi {
        u16* C;
        __device__ void operator()(int m, int n, float v) const {
            C[(size_t)m * DD + n] = f2bf(v);
        }
    } epi{C};
    mfma_gemm<64, 64>(A, B, SS, SS, SS, blockIdx.y * 64, 0, epi);
}

// ---------------- proj (template) ------------------------------------------
__global__ __launch_bounds__(256) void proj_gemm_kernel(
    const u16* __restrict__ ctx, const u16* __restrict__ Wt,
    const float* __restrict__ bias, float* __restrict__ out)
{
    struct Epi {
        float* out; const float* bias;
        __device__ void operator()(int m, int n, float v) const {
            out[(size_t)m * DD + n] = v + bias[n];
        }
    } epi{out, bias};
    mfma_gemm<128, 64>(ctx, Wt, DD, DD, DD, blockIdx.y * 128, blockIdx.x * 64, epi);
}

// ---------------- mix + softmax (R14 optimum, restored verbatim) -----------
// Phase-local registers + LDS round-trips; bf16 24 KB buffer (6 blocks/CU);
// no max pass; mix2 streams to global; zero bank conflicts. 56.3 us measured.
// R15/R16 MFMA-mix branch closed: transposed St layout cost 1.59e7 LDS bank
// conflict cycles (~40% of kernel) — net slower despite VALU 82->43%.
__global__ __launch_bounds__(256) void mix_softmax_kernel(
    const u16* __restrict__ attn, u16* __restrict__ attn2,
    const float* __restrict__ Wl, const float* __restrict__ bl,
    const float* __restrict__ Ww, const float* __restrict__ bw)
{
    __shared__ u16 buf[HH][SS];            // 24 KB bf16 working buffer
    __shared__ float invden[HH];

    const int tid  = threadIdx.x;
    const int wave = tid >> 6;
    const int lane = tid & 63;
    const int bL = blockIdx.x >> 10;
    const int qi = blockIdx.x & (SS - 1);
    const size_t gbase = ((size_t)bL * HH * SS + qi) * SS + tid * 4;
    const int kc = tid * 4;

    // stage-in: raw uint2 copy (no conversion), own columns, no barrier
#pragma unroll
    for (int h = 0; h < HH; ++h)
        *(uint2*)&buf[h][kc] = *(const uint2*)&attn[gbase + (size_t)h * SS * SS];

    // mix1: unpack own columns into phase-local vin, compute, pack back
    {
        float4 vin[HH];
#pragma unroll
        for (int h = 0; h < HH; ++h) {
            const uint2 u = *(const uint2*)&buf[h][kc];
            vin[h].x = b2f(u.x & 0xffff); vin[h].y = b2f(u.x >> 16);
            vin[h].z = b2f(u.y & 0xffff); vin[h].w = b2f(u.y >> 16);
        }
#pragma unroll
        for (int g = 0; g < HH; ++g) {
            float4 s = {bl[g], bl[g], bl[g], bl[g]};
#pragma unroll
            for (int h = 0; h < HH; ++h) {
                const float w = Wl[h * HH + g];   // uniform -> s_load
                s.x += vin[h].x * w; s.y += vin[h].y * w;
                s.z += vin[h].z * w; s.w += vin[h].w * w;
            }
            uint2 p;
            p.x = pack2(s.x, s.y); p.y = pack2(s.z, s.w);
            *(uint2*)&buf[g][kc] = p;
        }
    }
    __syncthreads();

    // softmax: wave w handles heads {w, w+4, w+8}; exp (no max) + butterfly
#pragma unroll
    for (int rep = 0; rep < 3; ++rep) {
        const int g = rep * 4 + wave;
        float4 v[4];
#pragma unroll
        for (int j = 0; j < 4; ++j) {
            const uint2 u = *(const uint2*)&buf[g][lane * 4 + j * 256];
            v[j].x = b2f(u.x & 0xffff); v[j].y = b2f(u.x >> 16);
            v[j].z = b2f(u.y & 0xffff); v[j].w = b2f(u.y >> 16);
        }

        float ps = 0.f;
#pragma unroll
        for (int j = 0; j < 4; ++j) {
            v[j].x = __expf(v[j].x); v[j].y = __expf(v[j].y);
            v[j].z = __expf(v[j].z); v[j].w = __expf(v[j].w);
            ps += (v[j].x + v[j].y) + (v[j].z + v[j].w);
        }
#pragma unroll
        for (int off = 32; off; off >>= 1) ps += __shfl_xor(ps, off);

#pragma unroll
        for (int j = 0; j < 4; ++j) {
            uint2 p;
            p.x = pack2(v[j].x, v[j].y); p.y = pack2(v[j].z, v[j].w);
            *(uint2*)&buf[g][lane * 4 + j * 256] = p;
        }
        if (lane == 0) invden[g] = 1.0f / ps;
    }
    __syncthreads();

    // mix2: unpack own columns, fold 1/l, stream straight to global
    {
        float4 vin[HH];
#pragma unroll
        for (int h = 0; h < HH; ++h) {
            const uint2 u = *(const uint2*)&buf[h][kc];
            const float inv = invden[h];
            vin[h].x = b2f(u.x & 0xffff) * inv; vin[h].y = b2f(u.x >> 16) * inv;
            vin[h].z = b2f(u.y & 0xffff) * inv; vin[h].w = b2f(u.y >> 16) * inv;
        }
#pragma unroll
        for (int g = 0; g < HH; ++g) {
            float4 s = {bw[g], bw[g], bw[g], bw[g]};
#pragma unroll
            for (int h = 0; h < HH; ++h) {
                const float w = Ww[h * HH + g];   // uniform -> s_load
                s.x += vin[h].x * w; s.y += vin[h].y * w;
                s.z += vin[h].z * w; s.w += vin[h].w * w;
            }
            uint2 p;
            p.x = pack2(s.x, s.y); p.y = pack2(s.z, s.w);
            *(uint2*)&attn2[gbase + (size_t)g * SS * SS] = p;
        }
    }
}

// ---------------- conversion kernels ----------------

__global__ __launch_bounds__(256) void cvt_bf16_kernel(
    const float* __restrict__ in, u16* __restrict__ out, int n8)
{
    const int i = blockIdx.x * 256 + threadIdx.x;
    if (i >= n8) return;
    const float4 a = ((const float4*)in)[i * 2];
    const float4 b = ((const float4*)in)[i * 2 + 1];
    uint4 p;
    p.x = pack2(a.x, a.y); p.y = pack2(a.z, a.w);
    p.z = pack2(b.x, b.y); p.w = pack2(b.z, b.w);
    ((uint4*)out)[i] = p;
}

__global__ __launch_bounds__(256) void cvt_transpose_kernel(
    const float* __restrict__ in, u16* __restrict__ out, int R, int C)
{
    __shared__ float t[32][33];
    const int c0 = blockIdx.x * 32, r0 = blockIdx.y * 32;
    const int tr = threadIdx.x >> 3;
    const int tc = (threadIdx.x & 7) * 4;
    const float4 v = *(const float4*)&in[(size_t)(r0 + tr) * C + c0 + tc];
    t[tc + 0][tr] = v.x; t[tc + 1][tr] = v.y;
    t[tc + 2][tr] = v.z; t[tc + 3][tr] = v.w;
    __syncthreads();
    uint2 p;
    p.x = pack2(t[tr][tc + 0], t[tr][tc + 1]);
    p.y = pack2(t[tr][tc + 2], t[tr][tc + 3]);
    *(uint2*)&out[(size_t)(c0 + tr) * R + r0 + tc] = p;
}

// ---------------- launch ----------------
extern "C" void kernel_launch(void* const* d_in, const int* in_sizes, int n_in,
                              void* d_out, int out_size, void* d_ws, size_t ws_size,
                              hipStream_t stream)
{
    const float* x     = (const float*)d_in[0];
    const float* Wqkv  = (const float*)d_in[1];
    const float* bqkv  = (const float*)d_in[2];
    const float* Wl    = (const float*)d_in[3];
    const float* bl    = (const float*)d_in[4];
    const float* Ww    = (const float*)d_in[5];
    const float* bw    = (const float*)d_in[6];
    const float* Wproj = (const float*)d_in[7];
    const float* bproj = (const float*)d_in[8];
    float* out = (float*)d_out;

    // workspace (bf16 elems)
    const size_t N_XB  = (size_t)BB * SS * DD;
    const size_t N_QB  = (size_t)BB * HH * SS * DH;
    const size_t N_WT  = (size_t)DD * 3 * DD;
    const size_t N_WP  = (size_t)DD * DD;
    const size_t N_AT1 = (size_t)HH * SS * SS;

    u16* xb  = (u16*)d_ws;
    u16* qb  = xb  + N_XB;
    u16* kb  = qb  + N_QB;
    u16* vb  = kb  + N_QB;
    u16* vt  = vb  + N_QB;
    u16* ctx = vt  + N_QB;
    u16* Wqkv_t = ctx + N_XB;
    u16* Wproj_t = Wqkv_t + N_WT;
    u16* attn = Wproj_t + N_WP;

    const size_t fixed_bytes = (size_t)(N_XB * 2 + N_QB * 4 + N_WT + N_WP) * 2;
    int b_per = BB;
    while (b_per > 1 &&
           fixed_bytes + (size_t)b_per * N_AT1 * 2 * 2 > ws_size)
        b_per >>= 1;
    const int n_iter = BB / b_per;
    u16* attn2 = attn + (size_t)b_per * N_AT1;

    const dim3 blk(256);

    // 0) conversions
    cvt_bf16_kernel<<<dim3((N_XB / 8 + 255) / 256), blk, 0, stream>>>(x, xb, (int)(N_XB / 8));
    cvt_transpose_kernel<<<dim3(3 * DD / 32, DD / 32), blk, 0, stream>>>(Wqkv, Wqkv_t, DD, 3 * DD);
    cvt_transpose_kernel<<<dim3(DD / 32, DD / 32), blk, 0, stream>>>(Wproj, Wproj_t, DD, DD);

    // 1) QKV projection (qb scaled, kb, vb) + v transpose
    qkv_gemm_kernel<<<dim3(3 * DD / 128, BB * SS / 128), blk, 0, stream>>>(
        xb, Wqkv_t, bqkv, qb, kb, vb);
    vtrans_kernel<<<dim3(SS / 64, BB * HH), blk, 0, stream>>>(vb, vt);

    for (int it = 0; it < n_iter; ++it) {
        const int bh0 = it * b_per * HH;
        // 2) logits
        qk_gemm_kernel<<<dim3(SS / 128, SS / 128, b_per * HH), blk, 0, stream>>>(
            qb, kb, attn, bh0);
        // 3) mix1 + softmax + mix2
        mix_softmax_kernel<<<dim3(b_per * SS), blk, 0, stream>>>(
            attn, attn2, Wl, bl, Ww, bw);
        // 4) PV (64x64 tiles)
        pv_gemm_kernel<<<dim3(1, SS / 64, b_per * HH), blk, 0, stream>>>(
            attn2, vt, ctx, bh0);
    }

    // 5) output projection
    proj_gemm_kernel<<<dim3(DD / 64, BB * SS / 128), blk, 0, stream>>>(
        ctx, Wproj_t, bproj, out);
}

// Round 18
// 231.698 us; speedup vs baseline: 1.0516x; 1.0079x over previous
//
#include <hip/hip_runtime.h>
#include <cstdint>

// Problem constants: B=4, S=1024, D=768, H=12, dh=64
#define BB 4
#define SS 1024
#define DD 768
#define HH 12
#define DH 64

typedef unsigned short u16;
typedef unsigned int   u32;
typedef __attribute__((ext_vector_type(8))) short bf16x8;
typedef __attribute__((ext_vector_type(4))) float f32x4;

// fp32 -> bf16 RNE (finite values)
__device__ __forceinline__ u16 f2bf(float f) {
    u32 u = __float_as_uint(f);
    u += 0x7fffu + ((u >> 16) & 1u);
    return (u16)(u >> 16);
}
__device__ __forceinline__ float b2f(u32 lo16) {
    return __uint_as_float(lo16 << 16);
}

// pack two f32 -> packed bf16x2. gfx950 has V_CVT_PK_BF16_F32 (1 VALU op vs
// ~10 for the scalar RNE sequence). Guarded: falls back to scalar if the
// builtin is unavailable.
#if __has_builtin(__builtin_amdgcn_cvt_pk_bf16_f32)
__device__ __forceinline__ u32 pack2(float a, float b) {
    auto r = __builtin_amdgcn_cvt_pk_bf16_f32(a, b);
    u32 v; __builtin_memcpy(&v, &r, 4); return v;
}
#else
__device__ __forceinline__ u32 pack2(float a, float b) {
    return (u32)f2bf(a) | ((u32)f2bf(b) << 16);
}
#endif

// async global->LDS, 16 B per lane. GLOBAL pointer is PER-LANE; LDS dest is
// wave-uniform base, HW adds lane*16 (m104/m108).
#define ASYNC16(gp, lp) __builtin_amdgcn_global_load_lds( \
    (const __attribute__((address_space(1))) void*)(gp),  \
    (__attribute__((address_space(3))) void*)(lp), 16, 0, 0)

// ---------------- MFMA GEMM body (NT: A[M,K], B[N,K], both K-contiguous bf16) ----
// BK=32. Tile BM_ x BN_, 256 threads = 4 waves in 2x2.
// mfma_f32_16x16x32_bf16; frag layouts per learn_hip m89/m91:
//   A: lane holds A[m=lane&15][k=(lane>>4)*8 + j]
//   B: lane holds Bt[n=lane&15][k=(lane>>4)*8 + j]  (NT rows)
//   C/D: col = lane&15, row = (lane>>4)*4 + reg
template<int BM_, int BN_, class Epi>
__device__ __forceinline__ void mfma_gemm(
    const u16* __restrict__ A, const u16* __restrict__ B,
    int K, int lda, int ldb, int m0, int n0, const Epi& epi)
{
    constexpr int MI = BM_ / 32;
    constexpr int NJ = BN_ / 32;
    __shared__ u16 Alds[BM_ * 32];
    __shared__ u16 Blds[BN_ * 32];

    const int tid  = threadIdx.x;
    const int wave = tid >> 6;
    const int lane = tid & 63;
    const int wr = wave >> 1, wc = wave & 1;

    const int ar = lane >> 2;
    const int ac = (lane & 3) * 8;

    f32x4 acc[MI][NJ] = {};

    for (int k0 = 0; k0 < K; k0 += 32) {
        __syncthreads();
#pragma unroll
        for (int j = 0; j < BM_ / 64; ++j) {
            const int rb = wave * (BM_ / 4) + j * 16;
            ASYNC16(A + (size_t)(m0 + rb + ar) * lda + k0 + ac, &Alds[rb * 32]);
        }
#pragma unroll
        for (int j = 0; j < BN_ / 64; ++j) {
            const int rb = wave * (BN_ / 4) + j * 16;
            ASYNC16(B + (size_t)(n0 + rb + ar) * ldb + k0 + ac, &Blds[rb * 32]);
        }
        __syncthreads();

        bf16x8 af[MI], bfr[NJ];
#pragma unroll
        for (int mi = 0; mi < MI; ++mi)
            af[mi] = *(const bf16x8*)&Alds[(wr * (BM_ / 2) + mi * 16 + (lane & 15)) * 32 + (lane >> 4) * 8];
#pragma unroll
        for (int nj = 0; nj < NJ; ++nj)
            bfr[nj] = *(const bf16x8*)&Blds[(wc * (BN_ / 2) + nj * 16 + (lane & 15)) * 32 + (lane >> 4) * 8];
#pragma unroll
        for (int mi = 0; mi < MI; ++mi)
#pragma unroll
            for (int nj = 0; nj < NJ; ++nj)
                acc[mi][nj] = __builtin_amdgcn_mfma_f32_16x16x32_bf16(
                    af[mi], bfr[nj], acc[mi][nj], 0, 0, 0);
    }

#pragma unroll
    for (int mi = 0; mi < MI; ++mi)
#pragma unroll
        for (int nj = 0; nj < NJ; ++nj)
#pragma unroll
            for (int r = 0; r < 4; ++r)
                epi(m0 + wr * (BM_ / 2) + mi * 16 + (lane >> 4) * 4 + r,
                    n0 + wc * (BN_ / 2) + nj * 16 + (lane & 15),
                    acc[mi][nj][r]);
}

// padded Clds row length (u16)
#define CPAD 136

// ---------------- qkv GEMM (custom, LDS-coalesced epilogue) ----------------
__global__ __launch_bounds__(256) void qkv_gemm_kernel(
    const u16* __restrict__ xb, const u16* __restrict__ Wt,
    const float* __restrict__ bias,
    u16* __restrict__ qb, u16* __restrict__ kb, u16* __restrict__ vb)
{
    __shared__ u16 Alds[128 * 32];
    __shared__ u16 Blds[128 * 32];
    __shared__ u16 Clds[128 * CPAD];

    const int tid  = threadIdx.x;
    const int wave = tid >> 6;
    const int lane = tid & 63;
    const int wr = wave >> 1, wc = wave & 1;
    const int ar = lane >> 2;
    const int ac = (lane & 3) * 8;
    const int m0 = blockIdx.y * 128, n0 = blockIdx.x * 128;

    f32x4 acc[4][4] = {};

    for (int k0 = 0; k0 < DD; k0 += 32) {
        __syncthreads();
#pragma unroll
        for (int j = 0; j < 2; ++j) {
            const int rb = wave * 32 + j * 16;
            ASYNC16(xb + (size_t)(m0 + rb + ar) * DD + k0 + ac, &Alds[rb * 32]);
            ASYNC16(Wt + (size_t)(n0 + rb + ar) * DD + k0 + ac, &Blds[rb * 32]);
        }
        __syncthreads();

        bf16x8 af[4], bfr[4];
#pragma unroll
        for (int mi = 0; mi < 4; ++mi)
            af[mi] = *(const bf16x8*)&Alds[(wr * 64 + mi * 16 + (lane & 15)) * 32 + (lane >> 4) * 8];
#pragma unroll
        for (int nj = 0; nj < 4; ++nj)
            bfr[nj] = *(const bf16x8*)&Blds[(wc * 64 + nj * 16 + (lane & 15)) * 32 + (lane >> 4) * 8];
#pragma unroll
        for (int mi = 0; mi < 4; ++mi)
#pragma unroll
            for (int nj = 0; nj < 4; ++nj)
                acc[mi][nj] = __builtin_amdgcn_mfma_f32_16x16x32_bf16(
                    af[mi], bfr[nj], acc[mi][nj], 0, 0, 0);
    }

    const int c  = n0 / DD;
    const int w0 = n0 - c * DD;
    const int hA = w0 >> 6;
    const float qs = (c == 0) ? 0.125f : 1.0f;
#pragma unroll
    for (int mi = 0; mi < 4; ++mi)
#pragma unroll
        for (int nj = 0; nj < 4; ++nj)
#pragma unroll
            for (int r = 0; r < 4; ++r) {
                const int row = wr * 64 + mi * 16 + (lane >> 4) * 4 + r;
                const int col = wc * 64 + nj * 16 + (lane & 15);
                Clds[row * CPAD + col] = f2bf((acc[mi][nj][r] + bias[n0 + col]) * qs);
            }
    __syncthreads();

    u16* const dst = (c == 0) ? qb : (c == 1) ? kb : vb;
    const int b = m0 >> 10;
#pragma unroll
    for (int j = 0; j < 8; ++j) {
        const int idx = j * 256 + tid;
        const int row = idx >> 4, u4 = idx & 15;
        const int half = u4 >> 3, d8 = u4 & 7;
        const int h = hA + half;
        const int s = (m0 + row) & 1023;
        const uint4 v = *(const uint4*)&Clds[row * CPAD + half * 64 + d8 * 8];
        *(uint4*)&dst[(((size_t)(b * HH + h) << 10) + s) * DH + d8 * 8] = v;
    }
}

// ---------------- vb -> vt transpose (per bh: 1024x64 -> 64x1024) ----------
__global__ __launch_bounds__(256) void vtrans_kernel(
    const u16* __restrict__ vb, u16* __restrict__ vt)
{
    __shared__ u16 t[64 * 72];
    const int tid = threadIdx.x;
    const int bh = blockIdx.y;
    const int s0 = blockIdx.x * 64;
    const u16* src = vb + ((size_t)bh << 16) + (size_t)s0 * DH;

#pragma unroll
    for (int j = 0; j < 2; ++j) {
        const int idx = j * 256 + tid;
        const int row = idx >> 3, u4 = idx & 7;
        *(uint4*)&t[row * 72 + u4 * 8] = *(const uint4*)&src[row * DH + u4 * 8];
    }
    __syncthreads();

#pragma unroll
    for (int j = 0; j < 2; ++j) {
        const int idx = j * 256 + tid;
        const int d = idx >> 3, u4 = idx & 7;
        u16 tmp[8];
#pragma unroll
        for (int i = 0; i < 8; ++i) tmp[i] = t[(u4 * 8 + i) * 72 + d];
        *(uint4*)&vt[((size_t)bh * DH + d) * SS + s0 + u4 * 8] = *(const uint4*)tmp;
    }
}

// ---------------- qk GEMM (custom, LDS-coalesced epilogue) -----------------
__global__ __launch_bounds__(256) void qk_gemm_kernel(
    const u16* __restrict__ qb, const u16* __restrict__ kb,
    u16* __restrict__ attn, int bh0)
{
    __shared__ u16 Alds[128 * 32];
    __shared__ u16 Blds[128 * 32];
    __shared__ u16 Clds[128 * CPAD];

    const int tid  = threadIdx.x;
    const int wave = tid >> 6;
    const int lane = tid & 63;
    const int wr = wave >> 1, wc = wave & 1;
    const int ar = lane >> 2;
    const int ac = (lane & 3) * 8;
    const int m0 = blockIdx.y * 128, n0 = blockIdx.x * 128;

    const int bhL = blockIdx.z;
    const u16* A = qb + (size_t)(bh0 + bhL) * SS * DH;
    const u16* B = kb + (size_t)(bh0 + bhL) * SS * DH;
    u16* C = attn + (size_t)bhL * SS * SS;

    f32x4 acc[4][4] = {};

#pragma unroll
    for (int k0 = 0; k0 < DH; k0 += 32) {
        __syncthreads();
#pragma unroll
        for (int j = 0; j < 2; ++j) {
            const int rb = wave * 32 + j * 16;
            ASYNC16(A + (size_t)(m0 + rb + ar) * DH + k0 + ac, &Alds[rb * 32]);
            ASYNC16(B + (size_t)(n0 + rb + ar) * DH + k0 + ac, &Blds[rb * 32]);
        }
        __syncthreads();

        bf16x8 af[4], bfr[4];
#pragma unroll
        for (int mi = 0; mi < 4; ++mi)
            af[mi] = *(const bf16x8*)&Alds[(wr * 64 + mi * 16 + (lane & 15)) * 32 + (lane >> 4) * 8];
#pragma unroll
        for (int nj = 0; nj < 4; ++nj)
            bfr[nj] = *(const bf16x8*)&Blds[(wc * 64 + nj * 16 + (lane & 15)) * 32 + (lane >> 4) * 8];
#pragma unroll
        for (int mi = 0; mi < 4; ++mi)
#pragma unroll
            for (int nj = 0; nj < 4; ++nj)
                acc[mi][nj] = __builtin_amdgcn_mfma_f32_16x16x32_bf16(
                    af[mi], bfr[nj], acc[mi][nj], 0, 0, 0);
    }

#pragma unroll
    for (int mi = 0; mi < 4; ++mi)
#pragma unroll
        for (int nj = 0; nj < 4; ++nj)
#pragma unroll
            for (int r = 0; r < 4; ++r) {
                const int row = wr * 64 + mi * 16 + (lane >> 4) * 4 + r;
                const int col = wc * 64 + nj * 16 + (lane & 15);
                Clds[row * CPAD + col] = f2bf(acc[mi][nj][r]);
            }
    __syncthreads();

#pragma unroll
    for (int j = 0; j < 8; ++j) {
        const int idx = j * 256 + tid;
        const int row = idx >> 4, u4 = idx & 15;
        *(uint4*)&C[(size_t)(m0 + row) * SS + n0 + u4 * 8] =
            *(const uint4*)&Clds[row * CPAD + u4 * 8];
    }
}

// ---------------- pv (64x64 tile) ------------------------------------------
__global__ __launch_bounds__(256) void pv_gemm_kernel(
    const u16* __restrict__ attn2, const u16* __restrict__ vt,
    u16* __restrict__ ctx, int bh0)
{
    const int bhL = blockIdx.z;
    const int bh = bh0 + bhL;
    const int b = bh / HH, h = bh % HH;
    const u16* A = attn2 + (size_t)bhL * SS * SS;
    const u16* B = vt + (size_t)bh * DH * SS;
    u16* C = ctx + (size_t)b * SS * DD + h * DH;
    struct Epi {
        u16* C;
        __device__ void operator()(int m, int n, float v) const {
            C[(size_t)m * DD + n] = f2bf(v);
        }
    } epi{C};
    mfma_gemm<64, 64>(A, B, SS, SS, SS, blockIdx.y * 64, 0, epi);
}

// ---------------- proj (template) ------------------------------------------
__global__ __launch_bounds__(256) void proj_gemm_kernel(
    const u16* __restrict__ ctx, const u16* __restrict__ Wt,
    const float* __restrict__ bias, float* __restrict__ out)
{
    struct Epi {
        float* out; const float* bias;
        __device__ void operator()(int m, int n, float v) const {
            out[(size_t)m * DD + n] = v + bias[n];
        }
    } epi{out, bias};
    mfma_gemm<128, 64>(ctx, Wt, DD, DD, DD, blockIdx.y * 128, blockIdx.x * 64, epi);
}

// ---------------- mix + softmax (R14/R17 optimum + packed bf16 cvt) --------
// Phase-local registers + LDS round-trips; bf16 24 KB buffer (6 blocks/CU);
// no max pass; mix2 streams to global; zero bank conflicts. pack2 now uses
// v_cvt_pk_bf16_f32 (1 op vs ~10) — ~650 fewer VALU ops/thread.
__global__ __launch_bounds__(256) void mix_softmax_kernel(
    const u16* __restrict__ attn, u16* __restrict__ attn2,
    const float* __restrict__ Wl, const float* __restrict__ bl,
    const float* __restrict__ Ww, const float* __restrict__ bw)
{
    __shared__ u16 buf[HH][SS];            // 24 KB bf16 working buffer
    __shared__ float invden[HH];

    const int tid  = threadIdx.x;
    const int wave = tid >> 6;
    const int lane = tid & 63;
    const int bL = blockIdx.x >> 10;
    const int qi = blockIdx.x & (SS - 1);
    const size_t gbase = ((size_t)bL * HH * SS + qi) * SS + tid * 4;
    const int kc = tid * 4;

    // stage-in: raw uint2 copy (no conversion), own columns, no barrier
#pragma unroll
    for (int h = 0; h < HH; ++h)
        *(uint2*)&buf[h][kc] = *(const uint2*)&attn[gbase + (size_t)h * SS * SS];

    // mix1: unpack own columns into phase-local vin, compute, pack back
    {
        float4 vin[HH];
#pragma unroll
        for (int h = 0; h < HH; ++h) {
            const uint2 u = *(const uint2*)&buf[h][kc];
            vin[h].x = b2f(u.x & 0xffff); vin[h].y = b2f(u.x >> 16);
            vin[h].z = b2f(u.y & 0xffff); vin[h].w = b2f(u.y >> 16);
        }
#pragma unroll
        for (int g = 0; g < HH; ++g) {
            float4 s = {bl[g], bl[g], bl[g], bl[g]};
#pragma unroll
            for (int h = 0; h < HH; ++h) {
                const float w = Wl[h * HH + g];   // uniform -> s_load
                s.x += vin[h].x * w; s.y += vin[h].y * w;
                s.z += vin[h].z * w; s.w += vin[h].w * w;
            }
            uint2 p;
            p.x = pack2(s.x, s.y); p.y = pack2(s.z, s.w);
            *(uint2*)&buf[g][kc] = p;
        }
    }
    __syncthreads();

    // softmax: wave w handles heads {w, w+4, w+8}; exp (no max) + butterfly
#pragma unroll
    for (int rep = 0; rep < 3; ++rep) {
        const int g = rep * 4 + wave;
        float4 v[4];
#pragma unroll
        for (int j = 0; j < 4; ++j) {
            const uint2 u = *(const uint2*)&buf[g][lane * 4 + j * 256];
            v[j].x = b2f(u.x & 0xffff); v[j].y = b2f(u.x >> 16);
            v[j].z = b2f(u.y & 0xffff); v[j].w = b2f(u.y >> 16);
        }

        float ps = 0.f;
#pragma unroll
        for (int j = 0; j < 4; ++j) {
            v[j].x = __expf(v[j].x); v[j].y = __expf(v[j].y);
            v[j].z = __expf(v[j].z); v[j].w = __expf(v[j].w);
            ps += (v[j].x + v[j].y) + (v[j].z + v[j].w);
        }
#pragma unroll
        for (int off = 32; off; off >>= 1) ps += __shfl_xor(ps, off);

#pragma unroll
        for (int j = 0; j < 4; ++j) {
            uint2 p;
            p.x = pack2(v[j].x, v[j].y); p.y = pack2(v[j].z, v[j].w);
            *(uint2*)&buf[g][lane * 4 + j * 256] = p;
        }
        if (lane == 0) invden[g] = 1.0f / ps;
    }
    __syncthreads();

    // mix2: unpack own columns, fold 1/l, stream straight to global
    {
        float4 vin[HH];
#pragma unroll
        for (int h = 0; h < HH; ++h) {
            const uint2 u = *(const uint2*)&buf[h][kc];
            const float inv = invden[h];
            vin[h].x = b2f(u.x & 0xffff) * inv; vin[h].y = b2f(u.x >> 16) * inv;
            vin[h].z = b2f(u.y & 0xffff) * inv; vin[h].w = b2f(u.y >> 16) * inv;
        }
#pragma unroll
        for (int g = 0; g < HH; ++g) {
            float4 s = {bw[g], bw[g], bw[g], bw[g]};
#pragma unroll
            for (int h = 0; h < HH; ++h) {
                const float w = Ww[h * HH + g];   // uniform -> s_load
                s.x += vin[h].x * w; s.y += vin[h].y * w;
                s.z += vin[h].z * w; s.w += vin[h].w * w;
            }
            uint2 p;
            p.x = pack2(s.x, s.y); p.y = pack2(s.z, s.w);
            *(uint2*)&attn2[gbase + (size_t)g * SS * SS] = p;
        }
    }
}

// ---------------- conversion kernels ----------------

__global__ __launch_bounds__(256) void cvt_bf16_kernel(
    const float* __restrict__ in, u16* __restrict__ out, int n8)
{
    const int i = blockIdx.x * 256 + threadIdx.x;
    if (i >= n8) return;
    const float4 a = ((const float4*)in)[i * 2];
    const float4 b = ((const float4*)in)[i * 2 + 1];
    uint4 p;
    p.x = pack2(a.x, a.y); p.y = pack2(a.z, a.w);
    p.z = pack2(b.x, b.y); p.w = pack2(b.z, b.w);
    ((uint4*)out)[i] = p;
}

__global__ __launch_bounds__(256) void cvt_transpose_kernel(
    const float* __restrict__ in, u16* __restrict__ out, int R, int C)
{
    __shared__ float t[32][33];
    const int c0 = blockIdx.x * 32, r0 = blockIdx.y * 32;
    const int tr = threadIdx.x >> 3;
    const int tc = (threadIdx.x & 7) * 4;
    const float4 v = *(const float4*)&in[(size_t)(r0 + tr) * C + c0 + tc];
    t[tc + 0][tr] = v.x; t[tc + 1][tr] = v.y;
    t[tc + 2][tr] = v.z; t[tc + 3][tr] = v.w;
    __syncthreads();
    uint2 p;
    p.x = pack2(t[tr][tc + 0], t[tr][tc + 1]);
    p.y = pack2(t[tr][tc + 2], t[tr][tc + 3]);
    *(uint2*)&out[(size_t)(c0 + tr) * R + r0 + tc] = p;
}

// ---------------- launch ----------------
extern "C" void kernel_launch(void* const* d_in, const int* in_sizes, int n_in,
                              void* d_out, int out_size, void* d_ws, size_t ws_size,
                              hipStream_t stream)
{
    const float* x     = (const float*)d_in[0];
    const float* Wqkv  = (const float*)d_in[1];
    const float* bqkv  = (const float*)d_in[2];
    const float* Wl    = (const float*)d_in[3];
    const float* bl    = (const float*)d_in[4];
    const float* Ww    = (const float*)d_in[5];
    const float* bw    = (const float*)d_in[6];
    const float* Wproj = (const float*)d_in[7];
    const float* bproj = (const float*)d_in[8];
    float* out = (float*)d_out;

    // workspace (bf16 elems)
    const size_t N_XB  = (size_t)BB * SS * DD;
    const size_t N_QB  = (size_t)BB * HH * SS * DH;
    const size_t N_WT  = (size_t)DD * 3 * DD;
    const size_t N_WP  = (size_t)DD * DD;
    const size_t N_AT1 = (size_t)HH * SS * SS;

    u16* xb  = (u16*)d_ws;
    u16* qb  = xb  + N_XB;
    u16* kb  = qb  + N_QB;
    u16* vb  = kb  + N_QB;
    u16* vt  = vb  + N_QB;
    u16* ctx = vt  + N_QB;
    u16* Wqkv_t = ctx + N_XB;
    u16* Wproj_t = Wqkv_t + N_WT;
    u16* attn = Wproj_t + N_WP;

    const size_t fixed_bytes = (size_t)(N_XB * 2 + N_QB * 4 + N_WT + N_WP) * 2;
    int b_per = BB;
    while (b_per > 1 &&
           fixed_bytes + (size_t)b_per * N_AT1 * 2 * 2 > ws_size)
        b_per >>= 1;
    const int n_iter = BB / b_per;
    u16* attn2 = attn + (size_t)b_per * N_AT1;

    const dim3 blk(256);

    // 0) conversions
    cvt_bf16_kernel<<<dim3((N_XB / 8 + 255) / 256), blk, 0, stream>>>(x, xb, (int)(N_XB / 8));
    cvt_transpose_kernel<<<dim3(3 * DD / 32, DD / 32), blk, 0, stream>>>(Wqkv, Wqkv_t, DD, 3 * DD);
    cvt_transpose_kernel<<<dim3(DD / 32, DD / 32), blk, 0, stream>>>(Wproj, Wproj_t, DD, DD);

    // 1) QKV projection (qb scaled, kb, vb) + v transpose
    qkv_gemm_kernel<<<dim3(3 * DD / 128, BB * SS / 128), blk, 0, stream>>>(
        xb, Wqkv_t, bqkv, qb, kb, vb);
    vtrans_kernel<<<dim3(SS / 64, BB * HH), blk, 0, stream>>>(vb, vt);

    for (int it = 0; it < n_iter; ++it) {
        const int bh0 = it * b_per * HH;
        // 2) logits
        qk_gemm_kernel<<<dim3(SS / 128, SS / 128, b_per * HH), blk, 0, stream>>>(
            qb, kb, attn, bh0);
        // 3) mix1 + softmax + mix2
        mix_softmax_kernel<<<dim3(b_per * SS), blk, 0, stream>>>(
            attn, attn2, Wl, bl, Ww, bw);
        // 4) PV (64x64 tiles)
        pv_gemm_kernel<<<dim3(1, SS / 64, b_per * HH), blk, 0, stream>>>(
            attn2, vt, ctx, bh0);
    }

    // 5) output projection
    proj_gemm_kernel<<<dim3(DD / 64, BB * SS / 128), blk, 0, stream>>>(
        ctx, Wproj_t, bproj, out);
}